// Round 2
// baseline (659.561 us; speedup 1.0000x reference)
//
#include <hip/hip_runtime.h>
#include <math.h>

// Problem constants (fixed by setup_inputs)
#define BB 256
#define SS 1024
#define DD 512
#define CC 8                                  // s-chunks per batch
#define ROWS_PER_BLOCK (SS / CC)              // 128
#define WAVES_PER_BLOCK 4
#define ROWS_PER_WAVE (ROWS_PER_BLOCK / WAVES_PER_BLOCK)  // 32

typedef float f4 __attribute__((ext_vector_type(4)));

// 2*log2(e): tanh(z) = 1 - 2*rcp(exp2(z*C2) + 1), exact at +-inf
#define C2 2.885390081777926814f

__device__ __forceinline__ f4 ldnt(const float* p) {
    return __builtin_nontemporal_load((const f4*)p);
}

__device__ __forceinline__ float fexp2(float x) {
#if __has_builtin(__builtin_amdgcn_exp2f)
    return __builtin_amdgcn_exp2f(x);        // v_exp_f32, 1 trans op
#else
    return __expf(x * 0.69314718055994531f);
#endif
}

__device__ __forceinline__ float frcp(float x) {
#if __has_builtin(__builtin_amdgcn_rcpf)
    return __builtin_amdgcn_rcpf(x);         // v_rcp_f32, 1 trans op, no VCC
#else
    return 1.0f / x;
#endif
}

// p += sum_j (-2*w_j) * rcp(exp2(v_j*C2 + qc_j) + 1)
// (qc = q*C2 and m2w = -2*w precomputed; the "+sum(w)" term is folded into
//  the accumulator's initial value, so tanh contributes w*(1-2r) in total)
__device__ __forceinline__ float dot_part(f4 v, f4 qc, f4 m2w, float p) {
    p = fmaf(m2w.x, frcp(fexp2(fmaf(v.x, C2, qc.x)) + 1.0f), p);
    p = fmaf(m2w.y, frcp(fexp2(fmaf(v.y, C2, qc.y)) + 1.0f), p);
    p = fmaf(m2w.z, frcp(fexp2(fmaf(v.z, C2, qc.z)) + 1.0f), p);
    p = fmaf(m2w.w, frcp(fexp2(fmaf(v.w, C2, qc.w)) + 1.0f), p);
    return p;
}

// Kernel 1: fused tanh-score + exp-weighted accumulation (no max tracking:
// |score| <= sum|Wa_w| ~= 18, exp() safely in fp32 range; branchless body so
// consecutive row-pairs' shuffle/exp chains software-pipeline).
// One block = one (b, s-chunk); each wave owns 32 contiguous rows, processed
// in pairs with a shared 8-shuffle bisection reduction.
__global__ __launch_bounds__(256, 4) void memn2n_partial(
    const float* __restrict__ story, const float* __restrict__ query,
    const float* __restrict__ Wa_w,
    float* __restrict__ wsO, float* __restrict__ wsL)
{
    const int g = blockIdx.x;        // 0 .. BB*CC-1
    const int b = g / CC;
    const int c = g % CC;
    const int lane = threadIdx.x & 63;
    const int wave = threadIdx.x >> 6;

    // lane's two contiguous d-segments: [0,256) and [256,512), float4 each
    const int d0 = lane * 4;
    const int d1 = 256 + lane * 4;

    const f4 q0 = *(const f4*)(query + (size_t)b * DD + d0);
    const f4 q1 = *(const f4*)(query + (size_t)b * DD + d1);
    const f4 w0 = *(const f4*)(Wa_w + d0);
    const f4 w1 = *(const f4*)(Wa_w + d1);

    // hoisted constants: qc = q*C2, m2w = -2*w, wsum = this lane's sum(w)
    const f4 qc0 = q0 * C2;
    const f4 qc1 = q1 * C2;
    const f4 m2w0 = -2.0f * w0;
    const f4 m2w1 = -2.0f * w1;
    const float wsum = (w0.x + w0.y + w0.z + w0.w) +
                       (w1.x + w1.y + w1.z + w1.w);

    const int sBeg = c * ROWS_PER_BLOCK + wave * ROWS_PER_WAVE;
    const float* rowp = story + ((size_t)b * SS + sBeg) * DD;

    float l = 0.0f;
    f4 a0 = (f4)0.0f;
    f4 a1 = (f4)0.0f;

    // software-pipelined: next row-pair always in flight (4 x dwordx4)
    f4 n0a = ldnt(rowp + d0);
    f4 n0b = ldnt(rowp + d1);
    f4 n1a = ldnt(rowp + DD + d0);
    f4 n1b = ldnt(rowp + DD + d1);

    for (int it = 0; it < ROWS_PER_WAVE / 2; ++it) {
        const f4 c0a = n0a, c0b = n0b, c1a = n1a, c1b = n1b;
        const float* np = rowp + 2 * DD;
        if (it + 1 < ROWS_PER_WAVE / 2) {
            n0a = ldnt(np + d0);
            n0b = ldnt(np + d1);
            n1a = ldnt(np + DD + d0);
            n1b = ldnt(np + DD + d1);
        }
        rowp = np;

        // per-lane partial scores for the two rows (bias: softmax-invariant).
        // start from wsum so the net per-element term is w*tanh = w - 2*w*r
        float p0 = dot_part(c0b, qc1, m2w1, dot_part(c0a, qc0, m2w0, wsum));
        float p1 = dot_part(c1b, qc1, m2w1, dot_part(c1a, qc0, m2w0, wsum));

        // paired reduction: 8 shuffles for 2 rows.
        // step 1 (xor 32): low half takes row0, high half takes row1
        const float t0 = __shfl_xor(p0, 32, 64);
        const float t1 = __shfl_xor(p1, 32, 64);
        float s = (lane < 32) ? (p0 + t0) : (p1 + t1);
        // butterfly within 32-lane halves
        s += __shfl_xor(s, 16, 64);
        s += __shfl_xor(s, 8, 64);
        s += __shfl_xor(s, 4, 64);
        s += __shfl_xor(s, 2, 64);
        s += __shfl_xor(s, 1, 64);
        // exp once, then cross-distribute the exp'd value (saves 1 trans op)
        const float es = __expf(s);
        const float eo = __shfl_xor(es, 32, 64);
        const float pe0 = (lane < 32) ? es : eo;
        const float pe1 = (lane < 32) ? eo : es;

        l += pe0 + pe1;
        a0 += pe0 * c0a + pe1 * c1a;
        a1 += pe0 * c0b + pe1 * c1b;
    }

    // ---- block-level combine of 4 wave partials via LDS (plain sums) ----
    __shared__ float ll[WAVES_PER_BLOCK];
    __shared__ float lo[WAVES_PER_BLOCK][DD];   // 8 KiB

    *(f4*)(&lo[wave][d0]) = a0;
    *(f4*)(&lo[wave][d1]) = a1;
    if (lane == 0) ll[wave] = l;
    __syncthreads();

    const int t = threadIdx.x;  // 256 threads, each sums 2 d's across waves
    const float s0 = lo[0][t] + lo[1][t] + lo[2][t] + lo[3][t];
    const float s1 = lo[0][t + 256] + lo[1][t + 256] + lo[2][t + 256] + lo[3][t + 256];
    wsO[(size_t)g * DD + t] = s0;
    wsO[(size_t)g * DD + t + 256] = s1;
    if (t == 0)
        wsL[g] = ll[0] + ll[1] + ll[2] + ll[3];
}

// Kernel 2: merge the CC chunk-partials per batch and emit out[b, :].
__global__ __launch_bounds__(128) void memn2n_combine(
    const float* __restrict__ wsO, const float* __restrict__ wsL,
    float* __restrict__ out)
{
    const int b = blockIdx.x;
    const int t = threadIdx.x;          // 128 threads x float4 = 512 d's

    float L = 0.0f;
#pragma unroll
    for (int c = 0; c < CC; ++c)
        L += wsL[b * CC + c];
    const float inv = 1.0f / L;

    const int d = t * 4;
    f4 acc = (f4)0.0f;
#pragma unroll
    for (int c = 0; c < CC; ++c)
        acc += *(const f4*)(wsO + ((size_t)(b * CC + c)) * DD + d);
    acc *= inv;
    *(f4*)(out + (size_t)b * DD + d) = acc;
}

extern "C" void kernel_launch(void* const* d_in, const int* in_sizes, int n_in,
                              void* d_out, int out_size, void* d_ws, size_t ws_size,
                              hipStream_t stream) {
    const float* story = (const float*)d_in[0];   // [256,1024,512]
    const float* query = (const float*)d_in[1];   // [256,512]
    const float* Wa_w  = (const float*)d_in[2];   // [512]
    // d_in[3] = Wa_b: constant bias inside softmax -> mathematically irrelevant
    float* out = (float*)d_out;                   // [256,512]

    // ws layout: O [BB*CC*DD] | L [BB*CC]  (floats, ~4.2 MB)
    float* wsO = (float*)d_ws;
    float* wsL = wsO + (size_t)BB * CC * DD;

    memn2n_partial<<<BB * CC, 256, 0, stream>>>(story, query, Wa_w, wsO, wsL);
    memn2n_combine<<<BB, 128, 0, stream>>>(wsO, wsL, out);
}